// Round 12
// baseline (118.000 us; speedup 1.0000x reference)
//
#include <hip/hip_runtime.h>
#include <hip/hip_bf16.h>
#include <math.h>

#define N_NODES 10000
#define KNBR    16
#define EDGEF   32
#define HID     64
#define E_TOT   (N_NODES*KNBR)

#define EPB 256              // edges per block
#define TPB 256              // 4 waves; each wave owns 64 edges (NTILE m-tiles)
#define NTILE 4
#define NODES_PB 16
#define NSLICE 33            // K' = 1056 = 33 slices of 32 (last slice carries b2)
#define CHUNK 4              // slices per staged chunk
#define NCHUNK 8             // 8*4 = 32 main slices; bias slice separate

typedef float    f32x4 __attribute__((ext_vector_type(4)));
typedef _Float16 f16x8 __attribute__((ext_vector_type(8)));

#define BF1_HALVES (4*64*8)
#define BF2_HALVES (3*NSLICE*64*8)
#define WS_HALVES  (BF1_HALVES + BF2_HALVES)

// ---------------- prep: fragment-ready fp16 weights into d_ws ----------------
__global__ __launch_bounds__(256)
void esa_prep(const float* __restrict__ W1, const float* __restrict__ W2,
              const float* __restrict__ b2, _Float16* __restrict__ wsh)
{
    int i = blockIdx.x * 256 + threadIdx.x;
    if (i >= WS_HALVES) return;
    float v;
    if (i < BF1_HALVES) {
        int j = i & 7, lane = (i >> 3) & 63, t = i >> 9;
        int k = ((lane >> 4) << 3) + j;          // 0..31
        int n = (t << 4) + (lane & 15);          // 0..63
        v = W1[n * EDGEF + k];
    } else {
        int i2 = i - BF1_HALVES;
        int j = i2 & 7, lane = (i2 >> 3) & 63;
        int st = i2 >> 9;                        // t*33 + s
        int s = st % NSLICE, t = st / NSLICE;
        int k = (s << 5) + ((lane >> 4) << 3) + j;   // 0..1055
        int n = (t << 4) + (lane & 15);              // oml 0..47
        if (k < 1024)      v = W2[(n * 16 + (k >> 6)) * HID + (k & 63)];
        else if (k < 1040) v = b2[n * 16 + (k - 1024)];
        else               v = 0.f;
    }
    wsh[i] = (_Float16)v;
}

// async global->LDS, 16B per lane; LDS dest = wave-uniform base + lane*16
__device__ __forceinline__ void issue16(const _Float16* g, unsigned char* l) {
    __builtin_amdgcn_global_load_lds(
        (const __attribute__((address_space(1))) void*)g,
        (__attribute__((address_space(3))) void*)(void*)l, 16, 0, 0);
}

// ---------------- fused main kernel ----------------
// LDS (81920 B = 80 KB -> exactly 2 blocks/CU):
//   Bbuf @0      2 x 12288  ([buf][sc*3+t][lane][8] halves, chunk double-buffer)
//   hls  @24576  36864      ([256][72] f16)  dead after reg-preload
//   tpl  @61440  8192       ([256][16] f16)  dead after reg-preload
//   b2l  @69632  12288      ([256][12] f32)  live through attention
//   t2 overlay @0 53248     ([256][52] f32)  over Bbuf+hls, after GEMM
__global__ __launch_bounds__(TPB, 2)
void esa_main(const float* __restrict__ basis1, const float* __restrict__ basis2,
              const float* __restrict__ edge_feats, const float* __restrict__ f,
              const float* __restrict__ b1, const int* __restrict__ nbr,
              const _Float16* __restrict__ wsh, float* __restrict__ out)
{
    __shared__ __align__(16) unsigned char smem[81920];
    _Float16* hls = (_Float16*)(smem + 24576);
    _Float16* tpl = (_Float16*)(smem + 61440);
    float*    b2l = (float*)(smem + 69632);
    float*    t2  = (float*)smem;

    const int tid  = threadIdx.x;
    const int eb   = blockIdx.x * EPB;
    const int lane = tid & 63;
    const int w    = tid >> 6;      // 0..3
    const int lo   = lane & 15, hi = lane >> 4;

    const _Float16* Bf2 = wsh + BF1_HALVES;

    // ===== prefetch chunks 0,1 (latency hides under phases 0/0b) =====
    #pragma unroll
    for (int j = 0; j < 3; ++j) {
        issue16(Bf2 + ((size_t)((j*NSLICE + (0*CHUNK + w))*64) + lane)*8,
                smem + 0*12288 + (w*3 + j)*1024);
        issue16(Bf2 + ((size_t)((j*NSLICE + (1*CHUNK + w))*64) + lane)*8,
                smem + 1*12288 + (w*3 + j)*1024);
    }

    // ===== phase 0: tp (tensor-product coeffs) + bas2 stage — 1 edge/thread ===
    {
        const int el = tid;
        const int e  = eb + el;
        const int src = nbr[e];
        const float4* b1p = (const float4*)(basis1 + (size_t)e * 8);
        float4 u0 = b1p[0], u1 = b1p[1];                 // [d][l] layout
        float bl0[4] = {u0.x, u0.z, u1.x, u1.z};         // l=0, d=0..3
        float bl1[4] = {u0.y, u0.w, u1.y, u1.w};         // l=1
        const float4* fp = (const float4*)(f + (size_t)src * 32);
        _Float16 tpv[16];
        #pragma unroll
        for (int m = 0; m < 8; ++m) {
            float4 fv = fp[m];
            float a0 = fv.x*bl0[0] + fv.y*bl0[1] + fv.z*bl0[2] + fv.w*bl0[3];
            float a1 = fv.x*bl1[0] + fv.y*bl1[1] + fv.z*bl1[2] + fv.w*bl1[3];
            tpv[m*2+0] = (_Float16)a0;
            tpv[m*2+1] = (_Float16)a1;
        }
        *(f16x8*)(tpl + el*16)     = *(f16x8*)&tpv[0];
        *(f16x8*)(tpl + el*16 + 8) = *(f16x8*)&tpv[8];
        const float4* b2p = (const float4*)(basis2 + (size_t)e * 8);
        *(float4*)(b2l + el*12)     = b2p[0];
        *(float4*)(b2l + el*12 + 4) = b2p[1];
    }

    // ===== phase 0b: MLP1 via MFMA  h = relu(ef @ W1^T + b1) =====
    {
        float b1v[4];
        #pragma unroll
        for (int t = 0; t < 4; ++t) b1v[t] = b1[t*16 + lo];
        f16x8 afr[NTILE];
        #pragma unroll
        for (int mt = 0; mt < NTILE; ++mt) {
            size_t eg = (size_t)(eb + w*64 + mt*16 + lo);
            const float4* p = (const float4*)(edge_feats + eg*32 + hi*8);
            float4 x0 = p[0], x1 = p[1];
            f16x8 a;
            a[0]=(_Float16)x0.x; a[1]=(_Float16)x0.y; a[2]=(_Float16)x0.z; a[3]=(_Float16)x0.w;
            a[4]=(_Float16)x1.x; a[5]=(_Float16)x1.y; a[6]=(_Float16)x1.z; a[7]=(_Float16)x1.w;
            afr[mt] = a;
        }
        #pragma unroll
        for (int t = 0; t < 4; ++t) {
            f16x8 bfr = *(const f16x8*)(wsh + ((size_t)(t*64 + lane)) * 8);
            #pragma unroll
            for (int mt = 0; mt < NTILE; ++mt) {
                f32x4 acc = {0.f, 0.f, 0.f, 0.f};
                acc = __builtin_amdgcn_mfma_f32_16x16x32_f16(afr[mt], bfr, acc, 0, 0, 0);
                #pragma unroll
                for (int r = 0; r < 4; ++r) {
                    float hv = acc[r] + b1v[t];
                    hv = hv > 0.f ? hv : 0.f;
                    int el = w*64 + mt*16 + hi*4 + r;
                    hls[el*72 + t*16 + lo] = (_Float16)hv;
                }
            }
        }
    }
    __syncthreads();   // hls/tpl/b2l ready; prefetched chunks 0,1 landed

    // ===== phase 1: main GEMM  t2[e,oml] = sum_k' A'[e,k'] B'[k',oml] =====
    f32x4 acc[NTILE][3];
    #pragma unroll
    for (int mt = 0; mt < NTILE; ++mt)
        #pragma unroll
        for (int t = 0; t < 3; ++t)
            acc[mt][t] = (f32x4){0.f, 0.f, 0.f, 0.f};

    // preload ALL per-wave A-state into registers (hls/tpl dead afterwards)
    f16x8 tpA[NTILE], tpB[NTILE], hA[NTILE], hB[NTILE];
    #pragma unroll
    for (int mt = 0; mt < NTILE; ++mt) {
        const int e_mt = w*64 + mt*16 + lo;
        tpA[mt] = *(const f16x8*)(tpl + e_mt*16);
        tpB[mt] = *(const f16x8*)(tpl + e_mt*16 + 8);
        hA[mt]  = *(const f16x8*)(hls + e_mt*72 + hi*8);        // h cols 0..31
        hB[mt]  = *(const f16x8*)(hls + e_mt*72 + 32 + hi*8);   // h cols 32..63
    }

    // chunked, double-buffered K-loop: compute c from buf[c&1] while c+1 flies
    #pragma unroll
    for (int c = 0; c < NCHUNK; ++c) {
        const _Float16* buf = (const _Float16*)(smem + (c & 1)*12288);
        #pragma unroll
        for (int sc = 0; sc < CHUNK; ++sc) {
            const int s  = c*CHUNK + sc;     // compile-time after unroll
            const int cc = s >> 1;
            const int sh = s & 1;
            f16x8 bfr[3];
            #pragma unroll
            for (int t = 0; t < 3; ++t)
                bfr[t] = *(const f16x8*)(buf + ((sc*3 + t)*64 + lane)*8);
            #pragma unroll
            for (int mt = 0; mt < NTILE; ++mt) {
                _Float16 s0 = (cc < 8) ? tpA[mt][cc & 7] : tpB[mt][cc & 7];
                f16x8 a = (sh ? hB[mt] : hA[mt]) * (f16x8){s0,s0,s0,s0,s0,s0,s0,s0};
                #pragma unroll
                for (int t = 0; t < 3; ++t)
                    acc[mt][t] = __builtin_amdgcn_mfma_f32_16x16x32_f16(a, bfr[t], acc[mt][t], 0, 0, 0);
            }
        }
        __syncthreads();   // waves done reading buf; drains in-flight chunk c+1
        if (c + 2 < NCHUNK) {
            const int s = (c + 2)*CHUNK + w;
            #pragma unroll
            for (int j = 0; j < 3; ++j)
                issue16(Bf2 + ((size_t)((j*NSLICE + s)*64) + lane)*8,
                        smem + (c & 1)*12288 + (w*3 + j)*1024);
        }
    }

    // bias slice s=32: A' = tp (hi<2), B' = b2 frags (direct from L2, once)
    {
        f16x8 z = {(_Float16)0,(_Float16)0,(_Float16)0,(_Float16)0,
                   (_Float16)0,(_Float16)0,(_Float16)0,(_Float16)0};
        f16x8 bfr[3];
        #pragma unroll
        for (int t = 0; t < 3; ++t)
            bfr[t] = *(const f16x8*)(Bf2 + ((size_t)((t*NSLICE + 32)*64 + lane)) * 8);
        #pragma unroll
        for (int mt = 0; mt < NTILE; ++mt) {
            f16x8 a = (hi == 0) ? tpA[mt] : (hi == 1) ? tpB[mt] : z;
            #pragma unroll
            for (int t = 0; t < 3; ++t)
                acc[mt][t] = __builtin_amdgcn_mfma_f32_16x16x32_f16(a, bfr[t], acc[mt][t], 0, 0, 0);
        }
    }

    // t2 overlay: Bbuf + hls are dead (A-state in regs, last chunk consumed)
    #pragma unroll
    for (int mt = 0; mt < NTILE; ++mt)
        #pragma unroll
        for (int t = 0; t < 3; ++t)
            #pragma unroll
            for (int r = 0; r < 4; ++r)
                t2[(w*64 + mt*16 + hi*4 + r)*52 + t*16 + lo] = acc[mt][t][r];
    __syncthreads();

    // ===== phase 2: attention (wave w handles nodes it*4+w) =====
    // t2 columns are oml = om*2+l: k_ -> oml [0,16), q_ -> [16,32), v_ -> [32,48)
    const int kk = lane >> 2, hh = lane & 3;
    #pragma unroll
    for (int it = 0; it < 4; ++it) {
        int nl = it*4 + w;
        int node = blockIdx.x * NODES_PB + nl;
        int el = nl*16 + kk;
        const float* trow = t2 + el*52;
        float4 tk = *(const float4*)(trow + hh*4);
        float4 tq = *(const float4*)(trow + 16 + hh*4);
        float4 tv = *(const float4*)(trow + 32 + hh*4);
        float4 bl0 = *(const float4*)(b2l + el*12);
        float4 bl1 = *(const float4*)(b2l + el*12 + 4);
        float k8[8], q8[8], v8[8];
        const float* B0 = (const float*)&bl0;
        const float* B1 = (const float*)&bl1;
        #pragma unroll
        for (int d = 0; d < 4; ++d) {
            k8[d]   = tk.x*B0[d] + tk.y*B1[d];
            k8[4+d] = tk.z*B0[d] + tk.w*B1[d];
            q8[d]   = tq.x*B0[d] + tq.y*B1[d];
            q8[4+d] = tq.z*B0[d] + tq.w*B1[d];
            v8[d]   = tv.x*B0[d] + tv.y*B1[d];
            v8[4+d] = tv.z*B0[d] + tv.w*B1[d];
        }
        float qn[8];
        #pragma unroll
        for (int i = 0; i < 8; ++i) qn[i] = q8[i];
        #pragma unroll
        for (int m = 4; m <= 32; m <<= 1)
            #pragma unroll
            for (int i = 0; i < 8; ++i) qn[i] += __shfl_xor(qn[i], m);
        float s = 0.f;
        #pragma unroll
        for (int i = 0; i < 8; ++i) s += qn[i]*k8[i];
        s *= 0.0220970869120796f;   // (1/16) * 8^-0.5

        float mx = s;
        #pragma unroll
        for (int m = 4; m <= 32; m <<= 1) mx = fmaxf(mx, __shfl_xor(mx, m));
        float ex = __expf(s - mx);
        float den = ex;
        #pragma unroll
        for (int m = 4; m <= 32; m <<= 1) den += __shfl_xor(den, m);
        float wgt = ex / den;

        float o[8];
        #pragma unroll
        for (int i = 0; i < 8; ++i) o[i] = wgt * v8[i];
        #pragma unroll
        for (int m = 4; m <= 32; m <<= 1)
            #pragma unroll
            for (int i = 0; i < 8; ++i) o[i] += __shfl_xor(o[i], m);
        if (kk == 0) {
            float4* dst = (float4*)(out + (size_t)node*32 + hh*8);
            dst[0] = make_float4(o[0], o[1], o[2], o[3]);
            dst[1] = make_float4(o[4], o[5], o[6], o[7]);
        }
    }
}

extern "C" void kernel_launch(void* const* d_in, const int* in_sizes, int n_in,
                              void* d_out, int out_size, void* d_ws, size_t ws_size,
                              hipStream_t stream) {
    const float* basis1     = (const float*)d_in[0];
    const float* basis2     = (const float*)d_in[1];
    const float* edge_feats = (const float*)d_in[2];
    const float* f          = (const float*)d_in[3];
    const float* W1         = (const float*)d_in[4];
    const float* b1         = (const float*)d_in[5];
    const float* W2         = (const float*)d_in[6];
    const float* b2         = (const float*)d_in[7];
    const int*   nbr        = (const int*)d_in[8];
    float* out = (float*)d_out;
    _Float16* wsh = (_Float16*)d_ws;

    esa_prep<<<(WS_HALVES + 255)/256, 256, 0, stream>>>(W1, W2, b2, wsh);
    esa_main<<<E_TOT/EPB, TPB, 0, stream>>>(basis1, basis2, edge_feats, f,
                                            b1, nbr, wsh, out);
}

// Round 13
// 110.454 us; speedup vs baseline: 1.0683x; 1.0683x over previous
//
#include <hip/hip_runtime.h>
#include <hip/hip_bf16.h>
#include <math.h>

#define N_NODES 10000
#define KNBR    16
#define EDGEF   32
#define HID     64
#define E_TOT   (N_NODES*KNBR)

#define EPB 128              // edges per block
#define TPB 256              // 4 waves; each wave owns 32 edges (2 m-tiles)
#define NODES_PB 8
#define NSLICE 33            // K' = 1056 = 33 slices of 32 (last slice carries b2)
#define CHUNK 4              // slices per staged chunk
#define NCHUNK 8             // 8*4 = 32 main slices; bias slice separate

typedef float    f32x4 __attribute__((ext_vector_type(4)));
typedef _Float16 f16x8 __attribute__((ext_vector_type(8)));

#define BF1_HALVES (4*64*8)
#define BF2_HALVES (3*NSLICE*64*8)
#define WS_HALVES  (BF1_HALVES + BF2_HALVES)

// ---------------- prep: fragment-ready fp16 weights into d_ws ----------------
// W1 is emitted as the A-operand of h^T = W1 . ef^T with rows PERMUTED by
// sigma(t,m) = (t&1)*4 + (m&3) + 8*(m>>2) + 32*(t>>1), so that MLP1's MFMA
// output lands directly in the main GEMM's A-frag layout (no LDS transpose).
__global__ __launch_bounds__(256)
void esa_prep(const float* __restrict__ W1, const float* __restrict__ W2,
              const float* __restrict__ b2, _Float16* __restrict__ wsh)
{
    int i = blockIdx.x * 256 + threadIdx.x;
    if (i >= WS_HALVES) return;
    float v;
    if (i < BF1_HALVES) {
        int j = i & 7, lane = (i >> 3) & 63, t = i >> 9;
        int k = ((lane >> 4) << 3) + j;          // 0..31
        int m = lane & 15;                       // row within 16-tile
        int hid = (t & 1)*4 + (m & 3) + 8*(m >> 2) + 32*(t >> 1);
        v = W1[hid * EDGEF + k];
    } else {
        int i2 = i - BF1_HALVES;
        int j = i2 & 7, lane = (i2 >> 3) & 63;
        int st = i2 >> 9;                        // t*33 + s
        int s = st % NSLICE, t = st / NSLICE;
        int k = (s << 5) + ((lane >> 4) << 3) + j;   // 0..1055
        int n = (t << 4) + (lane & 15);              // oml 0..47
        if (k < 1024)      v = W2[(n * 16 + (k >> 6)) * HID + (k & 63)];
        else if (k < 1040) v = b2[n * 16 + (k - 1024)];
        else               v = 0.f;
    }
    wsh[i] = (_Float16)v;
}

// async global->LDS, 16B per lane; LDS dest = wave-uniform base + lane*16
__device__ __forceinline__ void issue16(const _Float16* g, unsigned char* l) {
    __builtin_amdgcn_global_load_lds(
        (const __attribute__((address_space(1))) void*)g,
        (__attribute__((address_space(3))) void*)(void*)l, 16, 0, 0);
}

// ---------------- fused main kernel ----------------
// LDS (34816 B -> 4 blocks/CU, 16 waves/CU):
//   Bbuf @0      2 x 12288  ([buf][sc*3+t][lane][8] halves, chunk double-buffer)
//   tpl  @24576  4096       ([128][16] f16)  dead after reg-preload
//   b2l  @28672  6144       ([128][12] f32)  live through attention
//   t2 overlay @0 26624     ([128][52] f32)  over Bbuf+tpl, after GEMM
__global__ __launch_bounds__(TPB, 4)
void esa_main(const float* __restrict__ basis1, const float* __restrict__ basis2,
              const float* __restrict__ edge_feats, const float* __restrict__ f,
              const float* __restrict__ b1, const int* __restrict__ nbr,
              const _Float16* __restrict__ wsh, float* __restrict__ out)
{
    __shared__ __align__(16) unsigned char smem[34816];
    _Float16* tpl = (_Float16*)(smem + 24576);
    float*    b2l = (float*)(smem + 28672);
    float*    t2  = (float*)smem;

    const int tid  = threadIdx.x;
    const int eb   = blockIdx.x * EPB;
    const int lane = tid & 63;
    const int w    = tid >> 6;      // 0..3
    const int lo   = lane & 15, hi = lane >> 4;

    const _Float16* Bf2 = wsh + BF1_HALVES;

    // ===== prefetch chunks 0,1 (latency hides under phases 0/0b) =====
    #pragma unroll
    for (int j = 0; j < 3; ++j) {
        issue16(Bf2 + ((size_t)((j*NSLICE + (0*CHUNK + w))*64) + lane)*8,
                smem + 0*12288 + (w*3 + j)*1024);
        issue16(Bf2 + ((size_t)((j*NSLICE + (1*CHUNK + w))*64) + lane)*8,
                smem + 1*12288 + (w*3 + j)*1024);
    }

    // ===== phase 0: tp (tensor-product coeffs) + bas2 stage =====
    {
        int el = tid >> 1, hf = tid & 1;
        int e  = eb + el;
        int src = nbr[e];
        const float4* b1p = (const float4*)(basis1 + (size_t)e * 8);
        float4 u0 = b1p[0], u1 = b1p[1];                 // [d][l] layout
        float bl0[4] = {u0.x, u0.z, u1.x, u1.z};         // l=0, d=0..3
        float bl1[4] = {u0.y, u0.w, u1.y, u1.w};         // l=1
        const float4* fp = (const float4*)(f + (size_t)src * 32 + hf * 16);
        _Float16 tpv[8];
        #pragma unroll
        for (int mm = 0; mm < 4; ++mm) {
            float4 fv = fp[mm];
            float a0 = fv.x*bl0[0] + fv.y*bl0[1] + fv.z*bl0[2] + fv.w*bl0[3];
            float a1 = fv.x*bl1[0] + fv.y*bl1[1] + fv.z*bl1[2] + fv.w*bl1[3];
            tpv[mm*2+0] = (_Float16)a0;
            tpv[mm*2+1] = (_Float16)a1;
        }
        *(f16x8*)(tpl + el*16 + hf*8) = *(f16x8*)tpv;
        float4 b2v = ((const float4*)(basis2 + (size_t)e * 8))[hf];
        *((float4*)(b2l + el*12) + hf) = b2v;
    }

    // ===== phase 0b: MLP1 via MFMA, h^T = W1 . ef^T -> A-frags in registers ===
    // output lane (lo,hi), tile t, reg r holds h[edge=e?+lo][hid=(t&1)*4+r+8hi+32(t>>1)]
    f16x8 hA[2], hB[2];   // k-halves of the main-GEMM A-operand, per m-tile
    {
        f16x8 afr[2];
        #pragma unroll
        for (int mt = 0; mt < 2; ++mt) {
            size_t eg = (size_t)(eb + w*32 + mt*16 + lo);
            const float4* p = (const float4*)(edge_feats + eg*32 + hi*8);
            float4 x0 = p[0], x1 = p[1];
            f16x8 a;
            a[0]=(_Float16)x0.x; a[1]=(_Float16)x0.y; a[2]=(_Float16)x0.z; a[3]=(_Float16)x0.w;
            a[4]=(_Float16)x1.x; a[5]=(_Float16)x1.y; a[6]=(_Float16)x1.z; a[7]=(_Float16)x1.w;
            afr[mt] = a;
        }
        #pragma unroll
        for (int t = 0; t < 4; ++t) {
            f16x8 wfr = *(const f16x8*)(wsh + ((size_t)(t*64 + lane)) * 8);
            float4 bq = *(const float4*)(b1 + (t & 1)*4 + 8*hi + 32*(t >> 1));
            const float* bqp = (const float*)&bq;
            #pragma unroll
            for (int mt = 0; mt < 2; ++mt) {
                f32x4 acc = {0.f, 0.f, 0.f, 0.f};
                acc = __builtin_amdgcn_mfma_f32_16x16x32_f16(wfr, afr[mt], acc, 0, 0, 0);
                #pragma unroll
                for (int r = 0; r < 4; ++r) {
                    float hv = acc[r] + bqp[r];
                    hv = hv > 0.f ? hv : 0.f;
                    _Float16 hx = (_Float16)hv;
                    if (t == 0)      hA[mt][r]     = hx;
                    else if (t == 1) hA[mt][4 + r] = hx;
                    else if (t == 2) hB[mt][r]     = hx;
                    else             hB[mt][4 + r] = hx;
                }
            }
        }
    }
    __syncthreads();   // tpl/b2l ready; prefetched chunks 0,1 landed

    // ===== phase 1: main GEMM  t2[e,oml] = sum_k' A'[e,k'] B'[k',oml] =====
    f32x4 acc[2][3];
    #pragma unroll
    for (int mt = 0; mt < 2; ++mt)
        #pragma unroll
        for (int t = 0; t < 3; ++t)
            acc[mt][t] = (f32x4){0.f, 0.f, 0.f, 0.f};

    const int e0 = w*32 + lo, e1 = e0 + 16;
    f16x8 tp0a = *(const f16x8*)(tpl + e0*16);
    f16x8 tp0b = *(const f16x8*)(tpl + e0*16 + 8);
    f16x8 tp1a = *(const f16x8*)(tpl + e1*16);
    f16x8 tp1b = *(const f16x8*)(tpl + e1*16 + 8);

    // chunked, double-buffered K-loop: compute c from buf[c&1] while c+1 flies
    #pragma unroll
    for (int c = 0; c < NCHUNK; ++c) {
        const _Float16* buf = (const _Float16*)(smem + (c & 1)*12288);
        #pragma unroll
        for (int sc = 0; sc < CHUNK; ++sc) {
            const int s  = c*CHUNK + sc;     // compile-time after unroll
            const int cc = s >> 1;
            const int sh = s & 1;
            f16x8 bfr[3];
            #pragma unroll
            for (int t = 0; t < 3; ++t)
                bfr[t] = *(const f16x8*)(buf + ((sc*3 + t)*64 + lane)*8);
            _Float16 s0 = (cc < 8) ? tp0a[cc & 7] : tp0b[cc & 7];
            _Float16 s1 = (cc < 8) ? tp1a[cc & 7] : tp1b[cc & 7];
            f16x8 a0 = (sh ? hB[0] : hA[0]) * (f16x8){s0,s0,s0,s0,s0,s0,s0,s0};
            f16x8 a1 = (sh ? hB[1] : hA[1]) * (f16x8){s1,s1,s1,s1,s1,s1,s1,s1};
            #pragma unroll
            for (int t = 0; t < 3; ++t) {
                acc[0][t] = __builtin_amdgcn_mfma_f32_16x16x32_f16(a0, bfr[t], acc[0][t], 0, 0, 0);
                acc[1][t] = __builtin_amdgcn_mfma_f32_16x16x32_f16(a1, bfr[t], acc[1][t], 0, 0, 0);
            }
        }
        __syncthreads();   // waves done reading buf; drains in-flight chunk c+1
        if (c + 2 < NCHUNK) {
            const int s = (c + 2)*CHUNK + w;
            #pragma unroll
            for (int j = 0; j < 3; ++j)
                issue16(Bf2 + ((size_t)((j*NSLICE + s)*64) + lane)*8,
                        smem + (c & 1)*12288 + (w*3 + j)*1024);
        }
    }

    // bias slice s=32: A' = tp (hi<2), B' = b2 frags (direct from L2, once)
    {
        f16x8 z = {(_Float16)0,(_Float16)0,(_Float16)0,(_Float16)0,
                   (_Float16)0,(_Float16)0,(_Float16)0,(_Float16)0};
        f16x8 a0 = (hi == 0) ? tp0a : (hi == 1) ? tp0b : z;
        f16x8 a1 = (hi == 0) ? tp1a : (hi == 1) ? tp1b : z;
        #pragma unroll
        for (int t = 0; t < 3; ++t) {
            f16x8 bfr = *(const f16x8*)(Bf2 + ((size_t)((t*NSLICE + 32)*64 + lane)) * 8);
            acc[0][t] = __builtin_amdgcn_mfma_f32_16x16x32_f16(a0, bfr, acc[0][t], 0, 0, 0);
            acc[1][t] = __builtin_amdgcn_mfma_f32_16x16x32_f16(a1, bfr, acc[1][t], 0, 0, 0);
        }
    }

    // t2 overlay: Bbuf + tpl are dead (A-state in regs, last chunk consumed)
    #pragma unroll
    for (int mt = 0; mt < 2; ++mt)
        #pragma unroll
        for (int t = 0; t < 3; ++t)
            #pragma unroll
            for (int r = 0; r < 4; ++r)
                t2[(w*32 + mt*16 + hi*4 + r)*52 + t*16 + lo] = acc[mt][t][r];
    __syncthreads();

    // ===== phase 2: attention (wave w handles nodes it*4+w) =====
    // t2 columns are oml = om*2+l: k_ -> oml [0,16), q_ -> [16,32), v_ -> [32,48)
    const int kk = lane >> 2, hh = lane & 3;
    #pragma unroll
    for (int it = 0; it < 2; ++it) {
        int nl = it*4 + w;
        int node = blockIdx.x * NODES_PB + nl;
        int el = nl*16 + kk;
        const float* trow = t2 + el*52;
        float4 tk = *(const float4*)(trow + hh*4);
        float4 tq = *(const float4*)(trow + 16 + hh*4);
        float4 tv = *(const float4*)(trow + 32 + hh*4);
        float4 bl0 = *(const float4*)(b2l + el*12);
        float4 bl1 = *(const float4*)(b2l + el*12 + 4);
        float k8[8], q8[8], v8[8];
        const float* B0 = (const float*)&bl0;
        const float* B1 = (const float*)&bl1;
        #pragma unroll
        for (int d = 0; d < 4; ++d) {
            k8[d]   = tk.x*B0[d] + tk.y*B1[d];
            k8[4+d] = tk.z*B0[d] + tk.w*B1[d];
            q8[d]   = tq.x*B0[d] + tq.y*B1[d];
            q8[4+d] = tq.z*B0[d] + tq.w*B1[d];
            v8[d]   = tv.x*B0[d] + tv.y*B1[d];
            v8[4+d] = tv.z*B0[d] + tv.w*B1[d];
        }
        float qn[8];
        #pragma unroll
        for (int i = 0; i < 8; ++i) qn[i] = q8[i];
        #pragma unroll
        for (int m = 4; m <= 32; m <<= 1)
            #pragma unroll
            for (int i = 0; i < 8; ++i) qn[i] += __shfl_xor(qn[i], m);
        float s = 0.f;
        #pragma unroll
        for (int i = 0; i < 8; ++i) s += qn[i]*k8[i];
        s *= 0.0220970869120796f;   // (1/16) * 8^-0.5

        float mx = s;
        #pragma unroll
        for (int m = 4; m <= 32; m <<= 1) mx = fmaxf(mx, __shfl_xor(mx, m));
        float ex = __expf(s - mx);
        float den = ex;
        #pragma unroll
        for (int m = 4; m <= 32; m <<= 1) den += __shfl_xor(den, m);
        float wgt = ex / den;

        float o[8];
        #pragma unroll
        for (int i = 0; i < 8; ++i) o[i] = wgt * v8[i];
        #pragma unroll
        for (int m = 4; m <= 32; m <<= 1)
            #pragma unroll
            for (int i = 0; i < 8; ++i) o[i] += __shfl_xor(o[i], m);
        if (kk == 0) {
            float4* dst = (float4*)(out + (size_t)node*32 + hh*8);
            dst[0] = make_float4(o[0], o[1], o[2], o[3]);
            dst[1] = make_float4(o[4], o[5], o[6], o[7]);
        }
    }
}

extern "C" void kernel_launch(void* const* d_in, const int* in_sizes, int n_in,
                              void* d_out, int out_size, void* d_ws, size_t ws_size,
                              hipStream_t stream) {
    const float* basis1     = (const float*)d_in[0];
    const float* basis2     = (const float*)d_in[1];
    const float* edge_feats = (const float*)d_in[2];
    const float* f          = (const float*)d_in[3];
    const float* W1         = (const float*)d_in[4];
    const float* b1         = (const float*)d_in[5];
    const float* W2         = (const float*)d_in[6];
    const float* b2         = (const float*)d_in[7];
    const int*   nbr        = (const int*)d_in[8];
    float* out = (float*)d_out;
    _Float16* wsh = (_Float16*)d_ws;

    esa_prep<<<(WS_HALVES + 255)/256, 256, 0, stream>>>(W1, W2, b2, wsh);
    esa_main<<<E_TOT/EPB, TPB, 0, stream>>>(basis1, basis2, edge_feats, f,
                                            b1, nbr, wsh, out);
}